// Round 5
// baseline (180.037 us; speedup 1.0000x reference)
//
#include <hip/hip_runtime.h>
#include <math.h>

// InterContactLoss on MI355X — round 4 (resubmit; previous bench hit
// GPUAcquisitionTimeout, kernel never ran): FUSED single pass.
//
// Round-3 evidence: v_pk_fma_f32 = 4 cyc/wave (no FLOP gain; fp32 pipe =
// 128 FLOP/cy/CU is the wall). Two-pass computes all 903M pairs twice ->
// 84.6M cy of pure fma. Fused pass computes 451.6M pairs ONCE, reducing
// both directions:
//   - row-min (human side): in registers, block covers full col-half ->
//     direct store, NO global atomics, NO init memset.
//   - col-min (object side): min3-fold 4 rows in-thread, then staggered
//     LDS ds_min_u32 (thread t updates col t+js: 256 distinct cols/step).
//   - B staged DUPLICATED [2048]x float4(-2bx,-2by,-2bz,bb) so the stagger
//     needs no mask: linear ds_read_b128 with immediate offsets.
//   - full d^2 = aa - 2ab + bb per pair (pk_add + 3 pk_fma), needed because
//     col-min must include per-row aa.
// Grid: 16bt x 2(pred/gt) x 7 row-stripes(1024) x 2 col-halves(1024) = 448.
// Pad rows get coords (1e18,0,0) -> d^2 ~ 1e36: never a col-min, not stored.

#define BT 16
#define VH 6890
#define VO 2048
#define NH (BT * VH)   // 110240
#define NO (BT * VO)   // 32768
#define NS 7           // row stripes of 1024
#define NC 2           // col halves of 1024

typedef float v2f __attribute__((ext_vector_type(2)));

// ---- VOP3P packed-fp32 macros (HW-verified in round 3: absmax 0) ----
// t = a * q.lo + q.hi   (broadcast both halves of q)
#define PK_FMA_ZB(t, a, q) \
    asm("v_pk_fma_f32 %0, %1, %2, %2 op_sel:[0,0,1] op_sel_hi:[1,0,1]" \
        : "=v"(t) : "v"(a), "v"(q))
// t += a * p.hi
#define PK_FMA_YB(t, a, p) \
    asm("v_pk_fma_f32 %0, %1, %2, %0 op_sel:[0,1,0] op_sel_hi:[1,1,1]" \
        : "+v"(t) : "v"(a), "v"(p))
// t += a * p.lo
#define PK_FMA_XB(t, a, p) \
    asm("v_pk_fma_f32 %0, %1, %2, %0 op_sel:[0,0,0] op_sel_hi:[1,0,1]" \
        : "+v"(t) : "v"(a), "v"(p))
// t = t + b (elementwise)
#define PK_ADD(t, b) \
    asm("v_pk_add_f32 %0, %0, %1 op_sel:[0,0] op_sel_hi:[1,1]" \
        : "+v"(t) : "v"(b))
// r = min(r, x, y)
#define MIN3(r, x, y) \
    asm("v_min3_f32 %0, %1, %2, %0" : "+v"(r) : "v"(x), "v"(y))

__global__ __launch_bounds__(256)
void mindist_fused(const float* __restrict__ hv,  const float* __restrict__ ov,
                   const float* __restrict__ ghv, const float* __restrict__ gov,
                   float* __restrict__ rowpart,   // [2][16][2][VH]
                   float* __restrict__ colpart,   // [2][16][7][2048]
                   unsigned int* __restrict__ accw)
{
    __shared__ float4       bq[2048];   // duplicated col data: 32 KB
    __shared__ unsigned int cm[2048];   // duplicated col-min:   8 KB

    // zero loss accumulators + done counter for the reduce kernel
    if (blockIdx.x == 0 && threadIdx.x < 16) accw[threadIdx.x] = 0u;

    const int tid = threadIdx.x;
    const int idx = blockIdx.x;
    const int c   = idx & 1;
    const int sc  = idx >> 1;          // [0,224)
    const int s   = sc % NS;
    const int rem = sc / NS;           // [0,32)
    const int bt  = rem & 15;
    const int pg  = rem >> 4;

    const float* A  = (pg ? ghv : hv) + (size_t)bt * VH * 3;
    const float* Bv = (pg ? gov : ov) + (size_t)bt * VO * 3;

    // ---- stage B col-half (duplicated) + init colmin ----
#pragma unroll
    for (int m = 0; m < 4; ++m) {
        const int jj  = tid + 256 * m;
        const int col = c * 1024 + jj;
        const float bx = Bv[col * 3 + 0];
        const float by = Bv[col * 3 + 1];
        const float bz = Bv[col * 3 + 2];
        const float4 w = make_float4(-2.f * bx, -2.f * by, -2.f * bz,
                                     fmaf(bx, bx, fmaf(by, by, bz * bz)));
        bq[jj] = w;  bq[jj + 1024] = w;
        cm[jj] = 0x7f7f7f7fu;  cm[jj + 1024] = 0x7f7f7f7fu;  // 3.39e38f
    }

    // ---- load 4 rows (2 v2f groups); pad rows -> (1e18,0,0), aa=1e36 ----
    v2f ax[2], ay[2], az[2], aa[2];
#pragma unroll
    for (int g = 0; g < 2; ++g) {
        float x[2], y[2], z[2];
#pragma unroll
        for (int h = 0; h < 2; ++h) {
            const int r = s * 1024 + tid + (g * 2 + h) * 256;
            if (r < VH) { x[h] = A[r*3+0]; y[h] = A[r*3+1]; z[h] = A[r*3+2]; }
            else        { x[h] = 1.0e18f;  y[h] = 0.f;      z[h] = 0.f; }
        }
        ax[g] = (v2f){x[0], x[1]};
        ay[g] = (v2f){y[0], y[1]};
        az[g] = (v2f){z[0], z[1]};
        aa[g] = (v2f){fmaf(x[0],x[0],fmaf(y[0],y[0],z[0]*z[0])),
                      fmaf(x[1],x[1],fmaf(y[1],y[1],z[1]*z[1]))};
    }

    __syncthreads();

    const float4* bp = &bq[tid];
    float rm00 = 3.0e38f, rm01 = 3.0e38f, rm10 = 3.0e38f, rm11 = 3.0e38f;

    // ---- main loop: 2 cols per iter, 4 rows each ----
    for (int js = 0; js < 1024; js += 2) {
        const float4 wA = bp[js + 0];
        const float4 wB = bp[js + 1];
        const v2f pA = (v2f){wA.x, wA.y}, qA = (v2f){wA.z, wA.w};
        const v2f pB = (v2f){wB.x, wB.y}, qB = (v2f){wB.z, wB.w};

        v2f t0A, t1A, t0B, t1B;
        PK_FMA_ZB(t0A, az[0], qA); PK_FMA_YB(t0A, ay[0], pA);
        PK_FMA_XB(t0A, ax[0], pA); PK_ADD(t0A, aa[0]);
        PK_FMA_ZB(t1A, az[1], qA); PK_FMA_YB(t1A, ay[1], pA);
        PK_FMA_XB(t1A, ax[1], pA); PK_ADD(t1A, aa[1]);
        PK_FMA_ZB(t0B, az[0], qB); PK_FMA_YB(t0B, ay[0], pB);
        PK_FMA_XB(t0B, ax[0], pB); PK_ADD(t0B, aa[0]);
        PK_FMA_ZB(t1B, az[1], qB); PK_FMA_YB(t1B, ay[1], pB);
        PK_FMA_XB(t1B, ax[1], pB); PK_ADD(t1B, aa[1]);

        // row mins (2 cols folded per min3)
        MIN3(rm00, t0A.x, t0B.x);
        MIN3(rm01, t0A.y, t0B.y);
        MIN3(rm10, t1A.x, t1B.x);
        MIN3(rm11, t1A.y, t1B.y);

        // col mins: fold 4 rows, clamp, staggered LDS atomic (256 distinct cols/step)
        const float cvA = fmaxf(fminf(fminf(fminf(t0A.x, t0A.y), t1A.x), t1A.y), 0.f);
        const float cvB = fmaxf(fminf(fminf(fminf(t0B.x, t0B.y), t1B.x), t1B.y), 0.f);
        atomicMin(&cm[tid + js + 0], __float_as_uint(cvA));
        atomicMin(&cm[tid + js + 1], __float_as_uint(cvB));
    }

    // ---- row-min store (complete for this col-half; reduce folds the 2 halves) ----
    {
        float* rp = rowpart + ((size_t)((pg * 16 + bt) * 2 + c)) * VH;
        const int r0 = s * 1024 + tid;
        if (r0           < VH) rp[r0          ] = fmaxf(rm00, 0.f);
        if (r0 + 256     < VH) rp[r0 + 256    ] = fmaxf(rm01, 0.f);
        if (r0 + 512     < VH) rp[r0 + 512    ] = fmaxf(rm10, 0.f);
        if (r0 + 768     < VH) rp[r0 + 768    ] = fmaxf(rm11, 0.f);
    }

    __syncthreads();

    // ---- col-min partial store (fold the duplicate) ----
    float* cp = colpart + ((size_t)((pg * 16 + bt) * NS + s)) * 2048 + c * 1024;
#pragma unroll
    for (int m = 0; m < 4; ++m) {
        const int jj = tid + 256 * m;
        cp[jj] = fminf(__uint_as_float(cm[jj]), __uint_as_float(cm[jj + 1024]));
    }
}

// ---- fused per-element loss + accumulation + last-block finalize ----
// acc: [0..3] human {pos, bce_pos, bce_neg, huber}; [4..7] object; [8] done ctr.
#define NBLK_H 431   // ceil(110240/256)
#define NBLK_O 128   // 32768/256
#define NBLK   (NBLK_H + NBLK_O)

__global__ __launch_bounds__(256)
void reduce_finalize(const float* __restrict__ rowpart, const float* __restrict__ colpart,
                     float* __restrict__ acc, float* __restrict__ outp)
{
    const int b = blockIdx.x;
    float p2 = 3.0e38f, g2 = 3.0e38f;
    float* a4;
    bool valid;

    if (b < NBLK_H) {
        a4 = acc;
        const int i = b * 256 + threadIdx.x;
        valid = (i < NH);
        if (valid) {
            const int bt = i / VH;
            const int r  = i - bt * VH;
            const float* rp0 = rowpart + ((size_t)(bt * 2    )) * VH + r;   // pred c0
            const float* rg0 = rowpart + ((size_t)((16+bt)*2 )) * VH + r;   // gt c0
            p2 = fminf(rp0[0], rp0[VH]);
            g2 = fminf(rg0[0], rg0[VH]);
        }
    } else {
        a4 = acc + 4;
        const int i = (b - NBLK_H) * 256 + threadIdx.x;
        valid = true;
        const int bt = i >> 11;
        const int j  = i & 2047;
        const float* cp = colpart + ((size_t)(bt * NS)) * 2048 + j;
        const float* cg = colpart + ((size_t)((16 + bt) * NS)) * 2048 + j;
        float mp = 3.0e38f, mg = 3.0e38f;
#pragma unroll
        for (int s = 0; s < NS; ++s) {
            mp = fminf(mp, cp[s * 2048]);
            mg = fminf(mg, cg[s * 2048]);
        }
        p2 = mp; g2 = mg;
    }

    float t = 0.f, sp = 0.f, sn = 0.f, sh = 0.f;
    if (valid) {
        const float d  = sqrtf(p2);
        const float dg = sqrtf(g2);
        const float tt = (dg < 0.2f) ? 1.f : 0.f;

        const float z = (0.2f - d) * 100.0f;           // (DIST_THR - d)/ALPHA
        float p = 1.0f / (1.0f + expf(-z));
        p = fminf(fmaxf(p, 1e-6f), 1.0f - 1e-6f);
        const float bce = (tt > 0.5f) ? -logf(p) : -logf(1.0f - p);

        const float over = fmaxf(d - 0.1f, 0.0f);      // d - CONTACT_TGT
        const float hub  = (over < 0.01f) ? (0.5f * over * over) / 0.01f
                                          : (over - 0.5f * 0.01f);
        t  = tt;
        sp = tt * bce;
        sn = (1.0f - tt) * bce;
        sh = tt * hub;
    }
    for (int off = 32; off > 0; off >>= 1) {
        t  += __shfl_down(t,  off);
        sp += __shfl_down(sp, off);
        sn += __shfl_down(sn, off);
        sh += __shfl_down(sh, off);
    }
    __shared__ float wsum[4][4];
    const int wid = threadIdx.x >> 6, lane = threadIdx.x & 63;
    if (lane == 0) {
        wsum[wid][0] = t; wsum[wid][1] = sp; wsum[wid][2] = sn; wsum[wid][3] = sh;
    }
    __syncthreads();
    if (threadIdx.x == 0) {
        float s0 = 0, s1 = 0, s2 = 0, s3 = 0;
        for (int w = 0; w < 4; ++w) {
            s0 += wsum[w][0]; s1 += wsum[w][1]; s2 += wsum[w][2]; s3 += wsum[w][3];
        }
        atomicAdd(&a4[0], s0);
        atomicAdd(&a4[1], s1);
        atomicAdd(&a4[2], s2);
        atomicAdd(&a4[3], s3);

        __threadfence();
        const unsigned f = atomicAdd((unsigned int*)&acc[8], 1u);
        if (f == NBLK - 1) {
            float v[8];
            for (int q = 0; q < 8; ++q) v[q] = atomicAdd(&acc[q], 0.0f);
            const float Ph = v[0], SpH = v[1], SnH = v[2], ShH = v[3];
            const float Po = v[4], SpO = v[5], SnO = v[6], ShO = v[7];
            const float Nh = (float)NH, No = (float)NO;

            const float pwH = ((Nh - Ph) + 1e-6f) / (Ph + 1e-6f);
            const float pwO = ((No - Po) + 1e-6f) / (Po + 1e-6f);
            const float bceH = (pwH * SpH + SnH) / Nh;
            const float bceO = (pwO * SpO + SnO) / No;
            const float Lbce = 0.5f * (bceH + bceO);

            const float LdH = (Ph > 0.f) ? ShH / fmaxf(Ph, 1.f) : 0.f;
            const float LdO = (Po > 0.f) ? ShO / fmaxf(Po, 1.f) : 0.f;

            outp[0] = 0.5f * Lbce + (LdH + LdO);
        }
    }
}

extern "C" void kernel_launch(void* const* d_in, const int* in_sizes, int n_in,
                              void* d_out, int out_size, void* d_ws, size_t ws_size,
                              hipStream_t stream)
{
    const float* hv  = (const float*)d_in[0];
    const float* ov  = (const float*)d_in[1];
    const float* ghv = (const float*)d_in[2];
    const float* gov = (const float*)d_in[3];

    float* ws      = (float*)d_ws;
    float* rowpart = ws;                             // 2*16*2*VH   = 440960 f
    float* colpart = rowpart + 2 * 16 * 2 * VH;      // 2*16*7*2048 = 458752 f
    float* acc     = colpart + 2 * 16 * NS * 2048;   // 16 f (8 sums + ctr + pad)

    mindist_fused<<<BT * 2 * NS * NC, 256, 0, stream>>>(
        hv, ov, ghv, gov, rowpart, colpart, (unsigned int*)acc);

    reduce_finalize<<<NBLK, 256, 0, stream>>>(rowpart, colpart, acc, (float*)d_out);
}

// Round 6
// 177.570 us; speedup vs baseline: 1.0139x; 1.0139x over previous
//
#include <hip/hip_runtime.h>
#include <math.h>

// InterContactLoss on MI355X — round 6: two-pass, scalar-load B, no LDS.
//
// Evidence trail: r3 two-pass = 80us (VALU 71%, 9.8 cy/wave-pair; core is 7).
// r5 fused-pass = 94us (col-min overhead 17 cy/pair + 15% occupancy) -> reverted.
// This round: B columns are wave-uniform -> load via SMEM (s_load through K$),
// feed v_pk_fma_f32 straight from SGPR pairs with op_sel broadcast. No LDS,
// no syncthreads, no float4->v2f shuffling. Sign trick: accumulate
// t = a.b - 0.5*||b||^2, reduce with v_max3, d2 = aa - 2*max(t) -> no neg
// modifiers, no prep arrays.
// Fixed ~75us harness/graph floor observed across node counts; only kernel
// time matters. 2048 blocks (8/CU), VGPR target <=64 for 8 waves/SIMD.

#define BT 16
#define VH 6890
#define VO 2048
#define NH (BT * VH)   // 110240
#define NO (BT * VO)   // 32768

typedef float v2f __attribute__((ext_vector_type(2)));

// ---- VOP3P packed fp32, B operand from SGPR pair (1 distinct SGPR/instr) ----
// t = a * bcast(P.lo) + bcast(c.lo)
#define PKF_SL(t, a, P, c) \
    asm("v_pk_fma_f32 %0, %1, %2, %3 op_sel:[0,0,0] op_sel_hi:[1,0,0]" \
        : "=v"(t) : "v"(a), "s"(P), "v"(c))
// t = a * bcast(P.hi) + bcast(c.hi)
#define PKF_SH(t, a, P, c) \
    asm("v_pk_fma_f32 %0, %1, %2, %3 op_sel:[0,1,1] op_sel_hi:[1,1,1]" \
        : "=v"(t) : "v"(a), "s"(P), "v"(c))
// t += a * bcast(P.lo)     (op_sel fields verified on HW in rounds 3-5)
#define PKF_AL(t, a, P) \
    asm("v_pk_fma_f32 %0, %1, %2, %0 op_sel:[0,0,0] op_sel_hi:[1,0,1]" \
        : "+v"(t) : "v"(a), "s"(P))
// t += a * bcast(P.hi)
#define PKF_AH(t, a, P) \
    asm("v_pk_fma_f32 %0, %1, %2, %0 op_sel:[0,1,0] op_sel_hi:[1,1,1]" \
        : "+v"(t) : "v"(a), "s"(P))
// r = max(r, x, y)
#define MAX3(r, x, y) \
    asm("v_max3_f32 %0, %1, %2, %0" : "+v"(r) : "v"(x), "v"(y))

template<int SL>
__device__ __forceinline__
void sweep(const float* __restrict__ Bb, int b0, int jmax,
           const v2f (&ax)[4], const v2f (&ay)[4], const v2f (&az)[4],
           float (&rx)[4], float (&ry)[4])
{
#pragma unroll 4
    for (int j = 0; j < SL; j += 2) {
        const int j0 = min(b0 + j,     jmax);   // uniform clamp (tail slice only)
        const int j1 = min(b0 + j + 1, jmax);
        const float bx0 = Bb[3*j0+0], by0 = Bb[3*j0+1], bz0 = Bb[3*j0+2];
        const float bx1 = Bb[3*j1+0], by1 = Bb[3*j1+1], bz1 = Bb[3*j1+2];
        const v2f PX = (v2f){bx0, bx1};         // SGPR pairs
        const v2f PY = (v2f){by0, by1};
        const v2f PZ = (v2f){bz0, bz1};
        // bbn = -0.5*||b||^2 ; chain gives t = a.b - 0.5||b||^2 ; d2 = aa - 2*max t
        const float bbn0 = -0.5f * fmaf(bx0, bx0, fmaf(by0, by0, bz0 * bz0));
        const float bbn1 = -0.5f * fmaf(bx1, bx1, fmaf(by1, by1, bz1 * bz1));
        const v2f BB = (v2f){bbn0, bbn1};
#pragma unroll
        for (int k = 0; k < 4; ++k) {
            v2f tA, tB;
            PKF_SL(tA, az[k], PZ, BB);
            PKF_SH(tB, az[k], PZ, BB);
            PKF_AL(tA, ay[k], PY);
            PKF_AH(tB, ay[k], PY);
            PKF_AL(tA, ax[k], PX);
            PKF_AH(tB, ax[k], PX);
            MAX3(rx[k], tA.x, tB.x);
            MAX3(ry[k], tA.y, tB.y);
        }
    }
}

__global__ __launch_bounds__(256, 8)
void mindist_all(const float* __restrict__ hv,  const float* __restrict__ ov,
                 const float* __restrict__ ghv, const float* __restrict__ gov,
                 unsigned int* __restrict__ dh,  unsigned int* __restrict__ dov,
                 unsigned int* __restrict__ dhg, unsigned int* __restrict__ dog,
                 unsigned int* __restrict__ accw)
{
    // zero loss accumulators + done counter for the reduce kernel (next node)
    if (blockIdx.x == 0 && threadIdx.x < 16) accw[threadIdx.x] = 0u;

    const int tid = threadIdx.x;
    const int idx = blockIdx.x;

    const float *A, *Bb;
    unsigned int* out;
    int nA, bt, abk, b0, jmax;
    bool human;

    if (idx < 1024) {
        // human-owned rows (4 groups of 2048), B = object verts, 8 slices of 256
        const int p = idx >> 9;            // 0 = pred, 1 = gt
        const int r = idx & 511;
        abk = r & 3;
        bt  = (r >> 2) & 15;
        const int z = r >> 6;              // 0..7
        A   = (p ? ghv : hv) + (size_t)bt * VH * 3;
        Bb  = (p ? gov : ov) + (size_t)bt * VO * 3;
        out = p ? dhg : dh;
        nA = VH; b0 = z * 256; jmax = VO - 1; human = true;
    } else {
        // object-owned rows (2048), B = human verts, 32 slices of 216 (clamped tail)
        const int q = idx - 1024;
        const int p = q >> 9;
        const int r = q & 511;
        abk = 0;
        bt  = r & 15;
        const int z = r >> 4;              // 0..31
        A   = (p ? gov : ov) + (size_t)bt * VO * 3;
        Bb  = (p ? ghv : hv) + (size_t)bt * VH * 3;
        out = p ? dog : dov;
        nA = VO; b0 = z * 216; jmax = VH - 1; human = false;
    }

    // 8 rows/thread: row = abk*2048 + tid + m*256, packed (2k, 2k+1)
    const int rowb = abk * 2048 + tid;
    v2f ax[4], ay[4], az[4];
    float rx[4], ry[4];
#pragma unroll
    for (int k = 0; k < 4; ++k) {
        const int r0 = rowb + (2 * k    ) * 256;
        const int r1 = rowb + (2 * k + 1) * 256;
        const int i0 = (r0 < nA) ? r0 : 0;     // clamped load; never stored
        const int i1 = (r1 < nA) ? r1 : 0;
        ax[k] = (v2f){A[i0*3+0], A[i1*3+0]};
        ay[k] = (v2f){A[i0*3+1], A[i1*3+1]};
        az[k] = (v2f){A[i0*3+2], A[i1*3+2]};
        rx[k] = -3.0e38f; ry[k] = -3.0e38f;
    }

    if (human) sweep<256>(Bb, b0, jmax, ax, ay, az, rx, ry);
    else       sweep<216>(Bb, b0, jmax, ax, ay, az, rx, ry);

    // epilogue: d2 = max(aa - 2*maxt, 0); combine across slices via uint atomicMin
#pragma unroll
    for (int k = 0; k < 4; ++k) {
        const int r0 = rowb + (2 * k    ) * 256;
        const int r1 = rowb + (2 * k + 1) * 256;
        if (r0 < nA) {
            const float aa = fmaf(ax[k].x, ax[k].x, fmaf(ay[k].x, ay[k].x, az[k].x * az[k].x));
            const float d2 = fmaxf(fmaf(-2.0f, rx[k], aa), 0.f);
            atomicMin(&out[(size_t)bt * nA + r0], __float_as_uint(d2));
        }
        if (r1 < nA) {
            const float aa = fmaf(ax[k].y, ax[k].y, fmaf(ay[k].y, ay[k].y, az[k].y * az[k].y));
            const float d2 = fmaxf(fmaf(-2.0f, ry[k], aa), 0.f);
            atomicMin(&out[(size_t)bt * nA + r1], __float_as_uint(d2));
        }
    }
}

// ---- fused per-element loss + accumulation + last-block finalize ----
// acc: [0..3] human {pos, bce_pos, bce_neg, huber}; [4..7] object; [8] done ctr.
#define NBLK_H 431   // ceil(110240/256)
#define NBLK_O 128   // 32768/256
#define NBLK   (NBLK_H + NBLK_O)

__global__ __launch_bounds__(256)
void reduce_finalize(const float* __restrict__ dh2, const float* __restrict__ dhg2,
                     const float* __restrict__ do2, const float* __restrict__ dog2,
                     float* __restrict__ acc, float* __restrict__ outp)
{
    const int b = blockIdx.x;
    const float *p2, *g2;
    float* a4;
    int N, i0;
    if (b < NBLK_H) { p2 = dh2; g2 = dhg2; a4 = acc;     N = NH; i0 = b * 256; }
    else            { p2 = do2; g2 = dog2; a4 = acc + 4; N = NO; i0 = (b - NBLK_H) * 256; }

    const int i = i0 + threadIdx.x;
    float t = 0.f, sp = 0.f, sn = 0.f, sh = 0.f;
    if (i < N) {
        const float d  = sqrtf(p2[i]);
        const float dg = sqrtf(g2[i]);
        const float tt = (dg < 0.2f) ? 1.f : 0.f;

        const float z = (0.2f - d) * 100.0f;           // (DIST_THR - d)/ALPHA
        float p = 1.0f / (1.0f + expf(-z));
        p = fminf(fmaxf(p, 1e-6f), 1.0f - 1e-6f);
        const float bce = (tt > 0.5f) ? -logf(p) : -logf(1.0f - p);

        const float over = fmaxf(d - 0.1f, 0.0f);      // d - CONTACT_TGT
        const float hub  = (over < 0.01f) ? (0.5f * over * over) / 0.01f
                                          : (over - 0.5f * 0.01f);
        t  = tt;
        sp = tt * bce;
        sn = (1.0f - tt) * bce;
        sh = tt * hub;
    }
    for (int off = 32; off > 0; off >>= 1) {
        t  += __shfl_down(t,  off);
        sp += __shfl_down(sp, off);
        sn += __shfl_down(sn, off);
        sh += __shfl_down(sh, off);
    }
    __shared__ float wsum[4][4];
    const int wid = threadIdx.x >> 6, lane = threadIdx.x & 63;
    if (lane == 0) {
        wsum[wid][0] = t; wsum[wid][1] = sp; wsum[wid][2] = sn; wsum[wid][3] = sh;
    }
    __syncthreads();
    if (threadIdx.x == 0) {
        float s0 = 0, s1 = 0, s2 = 0, s3 = 0;
        for (int w = 0; w < 4; ++w) {
            s0 += wsum[w][0]; s1 += wsum[w][1]; s2 += wsum[w][2]; s3 += wsum[w][3];
        }
        atomicAdd(&a4[0], s0);
        atomicAdd(&a4[1], s1);
        atomicAdd(&a4[2], s2);
        atomicAdd(&a4[3], s3);

        __threadfence();
        const unsigned f = atomicAdd((unsigned int*)&acc[8], 1u);
        if (f == NBLK - 1) {
            float v[8];
            for (int q = 0; q < 8; ++q) v[q] = atomicAdd(&acc[q], 0.0f);
            const float Ph = v[0], SpH = v[1], SnH = v[2], ShH = v[3];
            const float Po = v[4], SpO = v[5], SnO = v[6], ShO = v[7];
            const float Nh = (float)NH, No = (float)NO;

            const float pwH = ((Nh - Ph) + 1e-6f) / (Ph + 1e-6f);
            const float pwO = ((No - Po) + 1e-6f) / (Po + 1e-6f);
            const float bceH = (pwH * SpH + SnH) / Nh;
            const float bceO = (pwO * SpO + SnO) / No;
            const float Lbce = 0.5f * (bceH + bceO);

            const float LdH = (Ph > 0.f) ? ShH / fmaxf(Ph, 1.f) : 0.f;
            const float LdO = (Po > 0.f) ? ShO / fmaxf(Po, 1.f) : 0.f;

            outp[0] = 0.5f * Lbce + (LdH + LdO);
        }
    }
}

extern "C" void kernel_launch(void* const* d_in, const int* in_sizes, int n_in,
                              void* d_out, int out_size, void* d_ws, size_t ws_size,
                              hipStream_t stream)
{
    const float* hv  = (const float*)d_in[0];
    const float* ov  = (const float*)d_in[1];
    const float* ghv = (const float*)d_in[2];
    const float* gov = (const float*)d_in[3];

    float* ws  = (float*)d_ws;
    float* dh  = ws;               // [NH] min d^2 human->object
    float* dov = dh  + NH;         // [NO]
    float* dhg = dov + NO;         // [NH] gt
    float* dog = dhg + NH;         // [NO] gt
    float* acc = dog + NO;         // [8] sums + [1] done ctr (+pad)

    // 0x7f7f7f7f = 3.3966e38f: > any clamped d^2, order-preserving uint init
    hipMemsetAsync(ws, 0x7f, (size_t)(2 * (NH + NO)) * sizeof(float), stream);

    mindist_all<<<2048, 256, 0, stream>>>(hv, ov, ghv, gov,
                                          (unsigned int*)dh, (unsigned int*)dov,
                                          (unsigned int*)dhg, (unsigned int*)dog,
                                          (unsigned int*)acc);

    reduce_finalize<<<NBLK, 256, 0, stream>>>(dh, dhg, dov, dog, acc, (float*)d_out);
}

// Round 7
// 167.510 us; speedup vs baseline: 1.0748x; 1.0601x over previous
//
#include <hip/hip_runtime.h>
#include <math.h>

// InterContactLoss on MI355X — round 7: MFMA (split-bf16, exact K=16) fused pass.
//
// d^2 = aa - 2ab + bb mapped onto ONE v_mfma_f32_32x32x16_bf16 per 32x32 tile:
//   A lane(row) k-slots:  g0: [ahx,ahy,ahz,alx,aly,alz,aah,aal]
//                         g1: [ahx,ahy,ahz,alx,aly,alz,  1,  1]
//   B lane(col) k-slots:  g0: [-2bhx,-2bhy,-2bhz,-2bhx,-2bhy,-2bhz, 1, 1]
//                         g1: [-2blx,-2bly,-2blz,-2blx,-2bly,-2blz,bbh,bbl]
//   dot = -2(ah+al)(bh+bl) + aa + bb  (split residual ~2^-18 -> d2 err ~3e-5)
// A/B k-map errors cancel (same map both sides); C/D layout is the HW-verified
// col=lane&31, row=(reg&3)+8*(reg>>2)+4*(lane>>5).
// Fusion: block owns 128 rows x ALL 2048 cols -> row-min completes in-block
// (registers + 5-level shfl butterfly, direct store); col-min: min3-tree fold
// per tile -> LDS ds_atomic_min -> one global atomicMin pass per block.
// Nodes: memset(colm) -> prep(B-frags + acc zero) -> mindist -> reduce+finalize.

#define BT 16
#define VH 6890
#define VO 2048
#define NH (BT * VH)   // 110240
#define NO (BT * VO)   // 32768
#define RBLK 54        // ceil(6890/128) row-blocks per problem
#define NPROB 32       // 16 bt x {pred,gt}

typedef __attribute__((ext_vector_type(8)))  short          short8;
typedef __attribute__((ext_vector_type(8)))  unsigned short ushort8;
typedef __attribute__((ext_vector_type(16))) float          f32x16;

__device__ __forceinline__ unsigned short bf16_rne(float f) {
    const unsigned int u = __float_as_uint(f);
    return (unsigned short)((u + 0x7FFFu + ((u >> 16) & 1u)) >> 16);
}
__device__ __forceinline__ float bf16_tof(unsigned short h) {
    return __uint_as_float(((unsigned int)h) << 16);
}

#define MIN3N(d, a, b, c) \
    asm("v_min3_f32 %0, %1, %2, %3" : "=v"(d) : "v"(a), "v"(b), "v"(c))

// ---- prep: build B fragments [prob][jt 64][lane 64][8 bf16] + zero acc ----
__global__ __launch_bounds__(256)
void prep_kernel(const float* __restrict__ ov, const float* __restrict__ gov,
                 unsigned short* __restrict__ Bfrag, unsigned int* __restrict__ acc)
{
    const int t = blockIdx.x * 256 + threadIdx.x;       // 65536 = [pg][bt][col]
    if (t < 16) acc[t] = 0u;
    const int col = t & 2047;
    const int bt  = (t >> 11) & 15;
    const int pg  = t >> 15;

    const float* B = (pg ? gov : ov) + ((size_t)bt * VO + col) * 3;
    const float bx = B[0], by = B[1], bz = B[2];
    const float m2x = -2.f * bx, m2y = -2.f * by, m2z = -2.f * bz;
    const float bb  = fmaf(bx, bx, fmaf(by, by, bz * bz));

    const unsigned short hx = bf16_rne(m2x), hy = bf16_rne(m2y), hz = bf16_rne(m2z);
    const unsigned short lx = bf16_rne(m2x - bf16_tof(hx));
    const unsigned short ly = bf16_rne(m2y - bf16_tof(hy));
    const unsigned short lz = bf16_rne(m2z - bf16_tof(hz));
    const unsigned short bh = bf16_rne(bb);
    const unsigned short bl = bf16_rne(bb - bf16_tof(bh));
    const unsigned short one = 0x3F80;

    const int prob = pg * 16 + bt;
    unsigned short* d0 = Bfrag + ((size_t)((prob * 64 + (col >> 5)) * 64 + (col & 31))) * 8;
    const ushort8 w0 = {hx, hy, hz, hx, hy, hz, one, one};   // lane c   (k-group 0)
    const ushort8 w1 = {lx, ly, lz, lx, ly, lz, bh, bl};     // lane c+32 (k-group 1)
    *(ushort8*)d0          = w0;
    *(ushort8*)(d0 + 256)  = w1;                             // +32 lanes * 8 shorts
}

// ---- fused mindist: 1728 blocks = 32 probs x 54 row-blocks(128 rows) ----
__global__ __launch_bounds__(256)
void mindist_mfma(const float* __restrict__ hv, const float* __restrict__ ghv,
                  const unsigned short* __restrict__ Bfrag,
                  float* __restrict__ rowm,          // [prob][VH] fp32 d2
                  unsigned int* __restrict__ colm)   // [prob][2048] uint(d2)
{
    __shared__ unsigned int cmin[2048];
    const int tid  = threadIdx.x;
    const int lane = tid & 63;
    const int wave = tid >> 6;
    const int prob = blockIdx.x / RBLK;
    const int rblk = blockIdx.x - prob * RBLK;
    const int pg = prob >> 4, bt = prob & 15;

    for (int i = tid; i < 2048; i += 256) cmin[i] = 0x7f7f7f7fu;

    // ---- A fragment: 32 rows per wave, split-bf16, pad rows -> x=1e4 ----
    const float* A = (pg ? ghv : hv) + (size_t)bt * VH * 3;
    const int row0 = rblk * 128 + wave * 32;
    const int r    = row0 + (lane & 31);
    float x, y, z;
    if (r < VH) { x = A[3*r]; y = A[3*r+1]; z = A[3*r+2]; }
    else        { x = 1.0e4f; y = 0.f;      z = 0.f; }
    const float aa = fmaf(x, x, fmaf(y, y, z * z));
    const unsigned short ahx = bf16_rne(x), ahy = bf16_rne(y), ahz = bf16_rne(z);
    const unsigned short alx = bf16_rne(x - bf16_tof(ahx));
    const unsigned short aly = bf16_rne(y - bf16_tof(ahy));
    const unsigned short alz = bf16_rne(z - bf16_tof(ahz));
    const unsigned short aah = bf16_rne(aa);
    const unsigned short aal = bf16_rne(aa - bf16_tof(aah));
    const int g = lane >> 5;
    ushort8 a8u;
    a8u[0] = ahx; a8u[1] = ahy; a8u[2] = ahz;
    a8u[3] = alx; a8u[4] = aly; a8u[5] = alz;
    a8u[6] = g ? (unsigned short)0x3F80 : aah;
    a8u[7] = g ? (unsigned short)0x3F80 : aal;
    const short8 a8 = (short8)a8u;

    __syncthreads();   // cmin init done

    const unsigned short* BF = Bfrag + (size_t)prob * (64 * 64 * 8);
    short8 bnext = *(const short8*)(BF + (size_t)lane * 8);

    const f32x16 kz = {0,0,0,0,0,0,0,0,0,0,0,0,0,0,0,0};
    f32x16 rm;
#pragma unroll
    for (int i = 0; i < 16; ++i) rm[i] = 3.0e38f;

    for (int jt = 0; jt < 64; ++jt) {
        const short8 bcur = bnext;
        if (jt < 63) bnext = *(const short8*)(BF + ((size_t)(jt + 1) * 64 + lane) * 8);

        f32x16 d2 = __builtin_amdgcn_mfma_f32_32x32x16_bf16(a8, bcur, kz, 0, 0, 0);

        // row-min accumulate (elementwise; butterfly deferred past the j-loop)
#pragma unroll
        for (int i = 0; i < 16; ++i) rm[i] = fminf(rm[i], d2[i]);

        // col-min: min3 tree over the 16 rows this lane holds, then LDS atomic
        float p0, p1, p2, p3, p4, q0, q1;
        MIN3N(p0, d2[0],  d2[1],  d2[2]);
        MIN3N(p1, d2[3],  d2[4],  d2[5]);
        MIN3N(p2, d2[6],  d2[7],  d2[8]);
        MIN3N(p3, d2[9],  d2[10], d2[11]);
        MIN3N(p4, d2[12], d2[13], d2[14]);
        MIN3N(q0, p0, p1, p2);
        MIN3N(q1, p3, p4, d2[15]);
        const float cv = fmaxf(fminf(q0, q1), 0.f);
        atomicMin(&cmin[jt * 32 + (lane & 31)], __float_as_uint(cv));
    }

    // ---- row-min butterfly across the 32 col-lanes (masks stay in-half) ----
#pragma unroll
    for (int i = 0; i < 16; ++i) {
        float v = rm[i];
        v = fminf(v, __shfl_xor(v, 1));
        v = fminf(v, __shfl_xor(v, 2));
        v = fminf(v, __shfl_xor(v, 4));
        v = fminf(v, __shfl_xor(v, 8));
        v = fminf(v, __shfl_xor(v, 16));
        rm[i] = v;
    }
    if ((lane & 31) == 0) {       // lanes 0 and 32 hold 16 rows each
        float* rout = rowm + (size_t)prob * VH;
#pragma unroll
        for (int i = 0; i < 16; ++i) {
            const int rr = row0 + (i & 3) + 8 * (i >> 2) + 4 * g;
            if (rr < VH) rout[rr] = fmaxf(rm[i], 0.f);
        }
    }

    __syncthreads();   // all tiles' col atomics done
    unsigned int* gc = colm + (size_t)prob * 2048;
    for (int i = tid; i < 2048; i += 256) atomicMin(&gc[i], cmin[i]);
}

// ---- fused per-element loss + accumulation + last-block finalize ----
#define NBLK_H 431   // ceil(110240/256)
#define NBLK_O 128   // 32768/256
#define NBLK   (NBLK_H + NBLK_O)

__global__ __launch_bounds__(256)
void reduce_finalize(const float* __restrict__ rowm, const unsigned int* __restrict__ colm,
                     float* __restrict__ acc, float* __restrict__ outp)
{
    const int b = blockIdx.x;
    float p2 = 3.0e38f, g2 = 3.0e38f;
    float* a4;
    bool valid;

    if (b < NBLK_H) {
        a4 = acc;
        const int i = b * 256 + threadIdx.x;
        valid = (i < NH);
        if (valid) {
            const int bt = i / VH;
            const int r  = i - bt * VH;
            p2 = rowm[(size_t)bt * VH + r];
            g2 = rowm[(size_t)(16 + bt) * VH + r];
        }
    } else {
        a4 = acc + 4;
        const int i = (b - NBLK_H) * 256 + threadIdx.x;
        valid = true;
        const int bt = i >> 11;
        const int j  = i & 2047;
        p2 = __uint_as_float(colm[(size_t)bt * 2048 + j]);
        g2 = __uint_as_float(colm[(size_t)(16 + bt) * 2048 + j]);
    }

    float t = 0.f, sp = 0.f, sn = 0.f, sh = 0.f;
    if (valid) {
        const float d  = sqrtf(p2);
        const float dg = sqrtf(g2);
        const float tt = (dg < 0.2f) ? 1.f : 0.f;

        const float z = (0.2f - d) * 100.0f;           // (DIST_THR - d)/ALPHA
        float p = 1.0f / (1.0f + expf(-z));
        p = fminf(fmaxf(p, 1e-6f), 1.0f - 1e-6f);
        const float bce = (tt > 0.5f) ? -logf(p) : -logf(1.0f - p);

        const float over = fmaxf(d - 0.1f, 0.0f);      // d - CONTACT_TGT
        const float hub  = (over < 0.01f) ? (0.5f * over * over) / 0.01f
                                          : (over - 0.5f * 0.01f);
        t  = tt;
        sp = tt * bce;
        sn = (1.0f - tt) * bce;
        sh = tt * hub;
    }
    for (int off = 32; off > 0; off >>= 1) {
        t  += __shfl_down(t,  off);
        sp += __shfl_down(sp, off);
        sn += __shfl_down(sn, off);
        sh += __shfl_down(sh, off);
    }
    __shared__ float wsum[4][4];
    const int wid = threadIdx.x >> 6, lane = threadIdx.x & 63;
    if (lane == 0) {
        wsum[wid][0] = t; wsum[wid][1] = sp; wsum[wid][2] = sn; wsum[wid][3] = sh;
    }
    __syncthreads();
    if (threadIdx.x == 0) {
        float s0 = 0, s1 = 0, s2 = 0, s3 = 0;
        for (int w = 0; w < 4; ++w) {
            s0 += wsum[w][0]; s1 += wsum[w][1]; s2 += wsum[w][2]; s3 += wsum[w][3];
        }
        atomicAdd(&a4[0], s0);
        atomicAdd(&a4[1], s1);
        atomicAdd(&a4[2], s2);
        atomicAdd(&a4[3], s3);

        __threadfence();
        const unsigned f = atomicAdd((unsigned int*)&acc[8], 1u);
        if (f == NBLK - 1) {
            float v[8];
            for (int q = 0; q < 8; ++q) v[q] = atomicAdd(&acc[q], 0.0f);
            const float Ph = v[0], SpH = v[1], SnH = v[2], ShH = v[3];
            const float Po = v[4], SpO = v[5], SnO = v[6], ShO = v[7];
            const float Nh = (float)NH, No = (float)NO;

            const float pwH = ((Nh - Ph) + 1e-6f) / (Ph + 1e-6f);
            const float pwO = ((No - Po) + 1e-6f) / (Po + 1e-6f);
            const float bceH = (pwH * SpH + SnH) / Nh;
            const float bceO = (pwO * SpO + SnO) / No;
            const float Lbce = 0.5f * (bceH + bceO);

            const float LdH = (Ph > 0.f) ? ShH / fmaxf(Ph, 1.f) : 0.f;
            const float LdO = (Po > 0.f) ? ShO / fmaxf(Po, 1.f) : 0.f;

            outp[0] = 0.5f * Lbce + (LdH + LdO);
        }
    }
}

extern "C" void kernel_launch(void* const* d_in, const int* in_sizes, int n_in,
                              void* d_out, int out_size, void* d_ws, size_t ws_size,
                              hipStream_t stream)
{
    const float* hv  = (const float*)d_in[0];
    const float* ov  = (const float*)d_in[1];
    const float* ghv = (const float*)d_in[2];
    const float* gov = (const float*)d_in[3];

    // ws layout (16B-aligned pieces):
    unsigned short* Bfrag = (unsigned short*)d_ws;                 // 32*64*64*8 u16 = 2MB
    float*          rowm  = (float*)(Bfrag + NPROB * 64 * 64 * 8); // [32][VH] = 882KB
    unsigned int*   colm  = (unsigned int*)(rowm + NPROB * VH);    // [32][2048] = 256KB
    float*          acc   = (float*)(colm + NPROB * 2048);         // 8 sums + ctr

    // init col-min arrays to +huge (order-preserving uint for non-neg floats)
    hipMemsetAsync(colm, 0x7f, (size_t)NPROB * 2048 * sizeof(unsigned int), stream);

    prep_kernel<<<256, 256, 0, stream>>>(ov, gov, Bfrag, (unsigned int*)acc);

    mindist_mfma<<<NPROB * RBLK, 256, 0, stream>>>(hv, ghv, Bfrag, rowm, colm);

    reduce_finalize<<<NBLK, 256, 0, stream>>>(rowm, colm, acc, (float*)d_out);
}

// Round 8
// 139.625 us; speedup vs baseline: 1.2894x; 1.1997x over previous
//
#include <hip/hip_runtime.h>
#include <math.h>

// InterContactLoss on MI355X — round 8: MFMA in arch VGPRs + software pipeline.
//
// r7 evidence: builtin mfma put d2/rm in AGPRs (VGPR_Count=32!) -> every
// fmin/min3 paid accvgpr_read/write: ~172 instr/iter vs ~28 expected,
// VALUBusy 84%, MfmaUtil 7.8%. This round:
//  - inline-asm v_mfma_f32_32x32x16_bf16 with "=v" D and "v" C (gfx950
//    unified file) -> everything in arch VGPRs, min3 operates directly.
//  - dual-tile software pipeline: load next B-frags -> s_nop x2 ->
//    reduce PREVIOUS two tiles -> issue two MFMAs. Spacing covers the
//    MFMA-write -> VALU-read hazard (asm volatile pins order).
//  - reduce per dual-tile: 16 in-place min3 (rm = min(rm,dA,dB)),
//    7-min3 tree + clamp + ds_min_u32 per tile.
// Everything else (split-bf16 exact-K=16 mapping, prep, reduce_finalize)
// unchanged from r7 (absmax was 0.0).

#define BT 16
#define VH 6890
#define VO 2048
#define NH (BT * VH)   // 110240
#define NO (BT * VO)   // 32768
#define RBLK 54        // ceil(6890/128) row-blocks per problem
#define NPROB 32       // 16 bt x {pred,gt}

typedef __attribute__((ext_vector_type(8)))  short          short8;
typedef __attribute__((ext_vector_type(8)))  unsigned short ushort8;
typedef __attribute__((ext_vector_type(16))) float          f32x16;

__device__ __forceinline__ unsigned short bf16_rne(float f) {
    const unsigned int u = __float_as_uint(f);
    return (unsigned short)((u + 0x7FFFu + ((u >> 16) & 1u)) >> 16);
}
__device__ __forceinline__ float bf16_tof(unsigned short h) {
    return __uint_as_float(((unsigned int)h) << 16);
}

// D/C in arch VGPRs; volatile pins program order (hazard spacing is ours).
#define MFMA_VV(d, a, b, c) \
    asm volatile("v_mfma_f32_32x32x16_bf16 %0, %1, %2, %3" \
                 : "=v"(d) : "v"(a), "v"(b), "v"(c))
// r = min(r, x, y) in-place
#define MIN3I(r, x, y) \
    asm volatile("v_min3_f32 %0, %1, %2, %0" : "+v"(r) : "v"(x), "v"(y))
// d = min(a, b, c)
#define MIN3N(d, a, b, c) \
    asm volatile("v_min3_f32 %0, %1, %2, %3" : "=v"(d) : "v"(a), "v"(b), "v"(c))
#define SNOP() asm volatile("s_nop 7")

// ---- prep: build B fragments [prob][jt 64][lane 64][8 bf16] + zero acc ----
__global__ __launch_bounds__(256)
void prep_kernel(const float* __restrict__ ov, const float* __restrict__ gov,
                 unsigned short* __restrict__ Bfrag, unsigned int* __restrict__ acc)
{
    const int t = blockIdx.x * 256 + threadIdx.x;       // 65536 = [pg][bt][col]
    if (t < 16) acc[t] = 0u;
    const int col = t & 2047;
    const int bt  = (t >> 11) & 15;
    const int pg  = t >> 15;

    const float* B = (pg ? gov : ov) + ((size_t)bt * VO + col) * 3;
    const float bx = B[0], by = B[1], bz = B[2];
    const float m2x = -2.f * bx, m2y = -2.f * by, m2z = -2.f * bz;
    const float bb  = fmaf(bx, bx, fmaf(by, by, bz * bz));

    const unsigned short hx = bf16_rne(m2x), hy = bf16_rne(m2y), hz = bf16_rne(m2z);
    const unsigned short lx = bf16_rne(m2x - bf16_tof(hx));
    const unsigned short ly = bf16_rne(m2y - bf16_tof(hy));
    const unsigned short lz = bf16_rne(m2z - bf16_tof(hz));
    const unsigned short bh = bf16_rne(bb);
    const unsigned short bl = bf16_rne(bb - bf16_tof(bh));
    const unsigned short one = 0x3F80;

    const int prob = pg * 16 + bt;
    unsigned short* d0 = Bfrag + ((size_t)((prob * 64 + (col >> 5)) * 64 + (col & 31))) * 8;
    const ushort8 w0 = {hx, hy, hz, hx, hy, hz, one, one};   // lane c    (k 0..7)
    const ushort8 w1 = {lx, ly, lz, lx, ly, lz, bh, bl};     // lane c+32 (k 8..15)
    *(ushort8*)d0          = w0;
    *(ushort8*)(d0 + 256)  = w1;
}

// ---- fused mindist: 1728 blocks = 32 probs x 54 row-blocks(128 rows) ----
__global__ __launch_bounds__(256, 4)
void mindist_mfma(const float* __restrict__ hv, const float* __restrict__ ghv,
                  const unsigned short* __restrict__ Bfrag,
                  float* __restrict__ rowm,          // [prob][VH] fp32 d2
                  unsigned int* __restrict__ colm)   // [prob][2048] uint(d2)
{
    __shared__ unsigned int cmin[2048];
    const int tid  = threadIdx.x;
    const int lane = tid & 63;
    const int wave = tid >> 6;
    const int prob = blockIdx.x / RBLK;
    const int rblk = blockIdx.x - prob * RBLK;
    const int pg = prob >> 4, bt = prob & 15;

    for (int i = tid; i < 2048; i += 256) cmin[i] = 0x7f7f7f7fu;

    // ---- A fragment: 32 rows per wave, split-bf16, pad rows -> x=1e4 ----
    const float* A = (pg ? ghv : hv) + (size_t)bt * VH * 3;
    const int row0 = rblk * 128 + wave * 32;
    const int r    = row0 + (lane & 31);
    float x, y, z;
    if (r < VH) { x = A[3*r]; y = A[3*r+1]; z = A[3*r+2]; }
    else        { x = 1.0e4f; y = 0.f;      z = 0.f; }
    const float aa = fmaf(x, x, fmaf(y, y, z * z));
    const unsigned short ahx = bf16_rne(x), ahy = bf16_rne(y), ahz = bf16_rne(z);
    const unsigned short alx = bf16_rne(x - bf16_tof(ahx));
    const unsigned short aly = bf16_rne(y - bf16_tof(ahy));
    const unsigned short alz = bf16_rne(z - bf16_tof(ahz));
    const unsigned short aah = bf16_rne(aa);
    const unsigned short aal = bf16_rne(aa - bf16_tof(aah));
    const int g = lane >> 5;
    ushort8 a8u;
    a8u[0] = ahx; a8u[1] = ahy; a8u[2] = ahz;
    a8u[3] = alx; a8u[4] = aly; a8u[5] = alz;
    a8u[6] = g ? (unsigned short)0x3F80 : aah;
    a8u[7] = g ? (unsigned short)0x3F80 : aal;
    const short8 a8 = (short8)a8u;

    __syncthreads();   // cmin init done

    const unsigned short* bptr = Bfrag + (size_t)prob * (64 * 64 * 8) + (size_t)lane * 8;
    const int cl = lane & 31;

    f32x16 kz = {0,0,0,0,0,0,0,0,0,0,0,0,0,0,0,0};
    float rm[16];
#pragma unroll
    for (int i = 0; i < 16; ++i) rm[i] = 3.0e38f;

    f32x16 dA, dB;
    short8 bA = *(const short8*)(bptr);
    short8 bB = *(const short8*)(bptr + 512);
    bptr += 1024;
    MFMA_VV(dA, a8, bA, kz);
    MFMA_VV(dB, a8, bB, kz);

    for (int it = 1; it < 32; ++it) {
        bA = *(const short8*)(bptr);
        bB = *(const short8*)(bptr + 512);
        bptr += 1024;
        SNOP(); SNOP();   // MFMA-write -> VALU-read spacing insurance

        const int jt0 = 2 * it - 2;
        // row-min: fold both tiles into rm (in-place min3)
#pragma unroll
        for (int i = 0; i < 16; ++i) MIN3I(rm[i], dA[i], dB[i]);
        // col-min trees + LDS atomics
        {
            float p0, p1, p2, p3, p4, q0, q1;
            MIN3N(p0, dA[0],  dA[1],  dA[2]);
            MIN3N(p1, dA[3],  dA[4],  dA[5]);
            MIN3N(p2, dA[6],  dA[7],  dA[8]);
            MIN3N(p3, dA[9],  dA[10], dA[11]);
            MIN3N(p4, dA[12], dA[13], dA[14]);
            MIN3N(q0, p0, p1, p2);
            MIN3N(q1, p3, p4, dA[15]);
            atomicMin(&cmin[jt0 * 32 + cl],
                      __float_as_uint(fmaxf(fminf(q0, q1), 0.f)));
            MIN3N(p0, dB[0],  dB[1],  dB[2]);
            MIN3N(p1, dB[3],  dB[4],  dB[5]);
            MIN3N(p2, dB[6],  dB[7],  dB[8]);
            MIN3N(p3, dB[9],  dB[10], dB[11]);
            MIN3N(p4, dB[12], dB[13], dB[14]);
            MIN3N(q0, p0, p1, p2);
            MIN3N(q1, p3, p4, dB[15]);
            atomicMin(&cmin[(jt0 + 1) * 32 + cl],
                      __float_as_uint(fmaxf(fminf(q0, q1), 0.f)));
        }
        MFMA_VV(dA, a8, bA, kz);
        MFMA_VV(dB, a8, bB, kz);
    }

    // tail: reduce tiles 62,63
    SNOP(); SNOP();
#pragma unroll
    for (int i = 0; i < 16; ++i) MIN3I(rm[i], dA[i], dB[i]);
    {
        float p0, p1, p2, p3, p4, q0, q1;
        MIN3N(p0, dA[0],  dA[1],  dA[2]);
        MIN3N(p1, dA[3],  dA[4],  dA[5]);
        MIN3N(p2, dA[6],  dA[7],  dA[8]);
        MIN3N(p3, dA[9],  dA[10], dA[11]);
        MIN3N(p4, dA[12], dA[13], dA[14]);
        MIN3N(q0, p0, p1, p2);
        MIN3N(q1, p3, p4, dA[15]);
        atomicMin(&cmin[62 * 32 + cl], __float_as_uint(fmaxf(fminf(q0, q1), 0.f)));
        MIN3N(p0, dB[0],  dB[1],  dB[2]);
        MIN3N(p1, dB[3],  dB[4],  dB[5]);
        MIN3N(p2, dB[6],  dB[7],  dB[8]);
        MIN3N(p3, dB[9],  dB[10], dB[11]);
        MIN3N(p4, dB[12], dB[13], dB[14]);
        MIN3N(q0, p0, p1, p2);
        MIN3N(q1, p3, p4, dB[15]);
        atomicMin(&cmin[63 * 32 + cl], __float_as_uint(fmaxf(fminf(q0, q1), 0.f)));
    }

    // ---- row-min butterfly across the 32 col-lanes ----
#pragma unroll
    for (int i = 0; i < 16; ++i) {
        float v = rm[i];
        v = fminf(v, __shfl_xor(v, 1));
        v = fminf(v, __shfl_xor(v, 2));
        v = fminf(v, __shfl_xor(v, 4));
        v = fminf(v, __shfl_xor(v, 8));
        v = fminf(v, __shfl_xor(v, 16));
        rm[i] = v;
    }
    if ((lane & 31) == 0) {       // lanes 0 and 32 hold 16 rows each
        float* rout = rowm + (size_t)prob * VH;
#pragma unroll
        for (int i = 0; i < 16; ++i) {
            const int rr = row0 + (i & 3) + 8 * (i >> 2) + 4 * g;
            if (rr < VH) rout[rr] = fmaxf(rm[i], 0.f);
        }
    }

    __syncthreads();   // all tiles' col atomics done
    unsigned int* gc = colm + (size_t)prob * 2048;
    for (int i = tid; i < 2048; i += 256) atomicMin(&gc[i], cmin[i]);
}

// ---- fused per-element loss + accumulation + last-block finalize ----
#define NBLK_H 431   // ceil(110240/256)
#define NBLK_O 128   // 32768/256
#define NBLK   (NBLK_H + NBLK_O)

__global__ __launch_bounds__(256)
void reduce_finalize(const float* __restrict__ rowm, const unsigned int* __restrict__ colm,
                     float* __restrict__ acc, float* __restrict__ outp)
{
    const int b = blockIdx.x;
    float p2 = 3.0e38f, g2 = 3.0e38f;
    float* a4;
    bool valid;

    if (b < NBLK_H) {
        a4 = acc;
        const int i = b * 256 + threadIdx.x;
        valid = (i < NH);
        if (valid) {
            const int bt = i / VH;
            const int r  = i - bt * VH;
            p2 = rowm[(size_t)bt * VH + r];
            g2 = rowm[(size_t)(16 + bt) * VH + r];
        }
    } else {
        a4 = acc + 4;
        const int i = (b - NBLK_H) * 256 + threadIdx.x;
        valid = true;
        const int bt = i >> 11;
        const int j  = i & 2047;
        p2 = __uint_as_float(colm[(size_t)bt * 2048 + j]);
        g2 = __uint_as_float(colm[(size_t)(16 + bt) * 2048 + j]);
    }

    float t = 0.f, sp = 0.f, sn = 0.f, sh = 0.f;
    if (valid) {
        const float d  = sqrtf(p2);
        const float dg = sqrtf(g2);
        const float tt = (dg < 0.2f) ? 1.f : 0.f;

        const float z = (0.2f - d) * 100.0f;           // (DIST_THR - d)/ALPHA
        float p = 1.0f / (1.0f + expf(-z));
        p = fminf(fmaxf(p, 1e-6f), 1.0f - 1e-6f);
        const float bce = (tt > 0.5f) ? -logf(p) : -logf(1.0f - p);

        const float over = fmaxf(d - 0.1f, 0.0f);      // d - CONTACT_TGT
        const float hub  = (over < 0.01f) ? (0.5f * over * over) / 0.01f
                                          : (over - 0.5f * 0.01f);
        t  = tt;
        sp = tt * bce;
        sn = (1.0f - tt) * bce;
        sh = tt * hub;
    }
    for (int off = 32; off > 0; off >>= 1) {
        t  += __shfl_down(t,  off);
        sp += __shfl_down(sp, off);
        sn += __shfl_down(sn, off);
        sh += __shfl_down(sh, off);
    }
    __shared__ float wsum[4][4];
    const int wid = threadIdx.x >> 6, lane = threadIdx.x & 63;
    if (lane == 0) {
        wsum[wid][0] = t; wsum[wid][1] = sp; wsum[wid][2] = sn; wsum[wid][3] = sh;
    }
    __syncthreads();
    if (threadIdx.x == 0) {
        float s0 = 0, s1 = 0, s2 = 0, s3 = 0;
        for (int w = 0; w < 4; ++w) {
            s0 += wsum[w][0]; s1 += wsum[w][1]; s2 += wsum[w][2]; s3 += wsum[w][3];
        }
        atomicAdd(&a4[0], s0);
        atomicAdd(&a4[1], s1);
        atomicAdd(&a4[2], s2);
        atomicAdd(&a4[3], s3);

        __threadfence();
        const unsigned f = atomicAdd((unsigned int*)&acc[8], 1u);
        if (f == NBLK - 1) {
            float v[8];
            for (int q = 0; q < 8; ++q) v[q] = atomicAdd(&acc[q], 0.0f);
            const float Ph = v[0], SpH = v[1], SnH = v[2], ShH = v[3];
            const float Po = v[4], SpO = v[5], SnO = v[6], ShO = v[7];
            const float Nh = (float)NH, No = (float)NO;

            const float pwH = ((Nh - Ph) + 1e-6f) / (Ph + 1e-6f);
            const float pwO = ((No - Po) + 1e-6f) / (Po + 1e-6f);
            const float bceH = (pwH * SpH + SnH) / Nh;
            const float bceO = (pwO * SpO + SnO) / No;
            const float Lbce = 0.5f * (bceH + bceO);

            const float LdH = (Ph > 0.f) ? ShH / fmaxf(Ph, 1.f) : 0.f;
            const float LdO = (Po > 0.f) ? ShO / fmaxf(Po, 1.f) : 0.f;

            outp[0] = 0.5f * Lbce + (LdH + LdO);
        }
    }
}

extern "C" void kernel_launch(void* const* d_in, const int* in_sizes, int n_in,
                              void* d_out, int out_size, void* d_ws, size_t ws_size,
                              hipStream_t stream)
{
    const float* hv  = (const float*)d_in[0];
    const float* ov  = (const float*)d_in[1];
    const float* ghv = (const float*)d_in[2];
    const float* gov = (const float*)d_in[3];

    unsigned short* Bfrag = (unsigned short*)d_ws;                 // 32*64*64*8 u16 = 2MB
    float*          rowm  = (float*)(Bfrag + NPROB * 64 * 64 * 8); // [32][VH]
    unsigned int*   colm  = (unsigned int*)(rowm + NPROB * VH);    // [32][2048]
    float*          acc   = (float*)(colm + NPROB * 2048);         // 8 sums + ctr

    hipMemsetAsync(colm, 0x7f, (size_t)NPROB * 2048 * sizeof(unsigned int), stream);

    prep_kernel<<<256, 256, 0, stream>>>(ov, gov, Bfrag, (unsigned int*)acc);

    mindist_mfma<<<NPROB * RBLK, 256, 0, stream>>>(hv, ghv, Bfrag, rowm, colm);

    reduce_finalize<<<NBLK, 256, 0, stream>>>(rowm, colm, acc, (float*)d_out);
}

// Round 9
// 133.690 us; speedup vs baseline: 1.3467x; 1.0444x over previous
//
#include <hip/hip_runtime.h>
#include <math.h>

// InterContactLoss on MI355X — round 9: MFMA with PHYSICAL-VGPR banks.
//
// r8 evidence: "=v" on 512-bit MFMA dst still landed in AGPRs (VGPR_Count=44
// vs ~76 needed) -> ~70 accvgpr-copy instrs/dual-iter (237 cy measured vs ~90
// clean). This round removes the allocator from the equation:
//  - inline-asm MFMA writes hardcoded v[40:55]/v[56:71] (bank0) and
//    v[72:87]/v[88:103] (bank1); all 64 regs in clobber lists.
//  - C operand is literal 0 (inline const legal in any src field) -> no kz.
//  - double-banked pipeline: per half-step {load next b-pair -> MFMA bank X
//    -> REDUCE bank Y (previous half-step)} -> MFMA results age ~100+ cy
//    before VALU reads them; no s_nop in steady state, zero copies.
//  - REDUCE: one asm blob: 16 row-fold min3 (rm tied "+v") + two 9-op col
//    trees that reuse the dying bank regs as temps; outputs early-clobber.
//  - colm init folded into prep (65536 threads = NPROB*2048 words); memset
//    node dropped. ~85us of dur is harness floor (256MB ws-poison fill @42.5us
//    + launch gaps) — only kernel time is controllable.

#define BT 16
#define VH 6890
#define VO 2048
#define NH (BT * VH)   // 110240
#define NO (BT * VO)   // 32768
#define RBLK 54        // ceil(6890/128) row-blocks per problem
#define NPROB 32       // 16 bt x {pred,gt}

typedef __attribute__((ext_vector_type(8)))  short          short8;
typedef __attribute__((ext_vector_type(8)))  unsigned short ushort8;

__device__ __forceinline__ unsigned short bf16_rne(float f) {
    const unsigned int u = __float_as_uint(f);
    return (unsigned short)((u + 0x7FFFu + ((u >> 16) & 1u)) >> 16);
}
__device__ __forceinline__ float bf16_tof(unsigned short h) {
    return __uint_as_float(((unsigned int)h) << 16);
}

#define CLOB_B0 "v40","v41","v42","v43","v44","v45","v46","v47", \
                "v48","v49","v50","v51","v52","v53","v54","v55", \
                "v56","v57","v58","v59","v60","v61","v62","v63", \
                "v64","v65","v66","v67","v68","v69","v70","v71"
#define CLOB_B1 "v72","v73","v74","v75","v76","v77","v78","v79", \
                "v80","v81","v82","v83","v84","v85","v86","v87", \
                "v88","v89","v90","v91","v92","v93","v94","v95", \
                "v96","v97","v98","v99","v100","v101","v102","v103"

// Two MFMAs into a physical bank; C = inline 0.
#define MFMA_B0(b0, b1) \
    asm volatile("v_mfma_f32_32x32x16_bf16 v[40:55], %0, %1, 0\n\t" \
                 "v_mfma_f32_32x32x16_bf16 v[56:71], %0, %2, 0" \
                 :: "v"(a8), "v"(b0), "v"(b1) : CLOB_B0)
#define MFMA_B1(b0, b1) \
    asm volatile("v_mfma_f32_32x32x16_bf16 v[72:87], %0, %1, 0\n\t" \
                 "v_mfma_f32_32x32x16_bf16 v[88:103], %0, %2, 0" \
                 :: "v"(a8), "v"(b0), "v"(b1) : CLOB_B1)

// Reduce one bank: 16 row-fold min3 into rm + two col trees (temps = bank regs).
#define REDUCE_B0(jt0) do { float cvA, cvB; \
    asm volatile( \
        "v_min3_f32 %2, %2, v40, v56\n\t"  "v_min3_f32 %3, %3, v41, v57\n\t" \
        "v_min3_f32 %4, %4, v42, v58\n\t"  "v_min3_f32 %5, %5, v43, v59\n\t" \
        "v_min3_f32 %6, %6, v44, v60\n\t"  "v_min3_f32 %7, %7, v45, v61\n\t" \
        "v_min3_f32 %8, %8, v46, v62\n\t"  "v_min3_f32 %9, %9, v47, v63\n\t" \
        "v_min3_f32 %10, %10, v48, v64\n\t" "v_min3_f32 %11, %11, v49, v65\n\t" \
        "v_min3_f32 %12, %12, v50, v66\n\t" "v_min3_f32 %13, %13, v51, v67\n\t" \
        "v_min3_f32 %14, %14, v52, v68\n\t" "v_min3_f32 %15, %15, v53, v69\n\t" \
        "v_min3_f32 %16, %16, v54, v70\n\t" "v_min3_f32 %17, %17, v55, v71\n\t" \
        "v_min3_f32 v40, v40, v41, v42\n\t" "v_min3_f32 v43, v43, v44, v45\n\t" \
        "v_min3_f32 v46, v46, v47, v48\n\t" "v_min3_f32 v49, v49, v50, v51\n\t" \
        "v_min3_f32 v52, v52, v53, v54\n\t" "v_min3_f32 v40, v40, v43, v46\n\t" \
        "v_min3_f32 v49, v49, v52, v55\n\t" "v_min_f32  v40, v40, v49\n\t" \
        "v_max_f32  %0, 0, v40\n\t" \
        "v_min3_f32 v56, v56, v57, v58\n\t" "v_min3_f32 v59, v59, v60, v61\n\t" \
        "v_min3_f32 v62, v62, v63, v64\n\t" "v_min3_f32 v65, v65, v66, v67\n\t" \
        "v_min3_f32 v68, v68, v69, v70\n\t" "v_min3_f32 v56, v56, v59, v62\n\t" \
        "v_min3_f32 v65, v65, v68, v71\n\t" "v_min_f32  v56, v56, v65\n\t" \
        "v_max_f32  %1, 0, v56" \
        : "=&v"(cvA), "=&v"(cvB), \
          "+v"(rm[0]), "+v"(rm[1]), "+v"(rm[2]),  "+v"(rm[3]), \
          "+v"(rm[4]), "+v"(rm[5]), "+v"(rm[6]),  "+v"(rm[7]), \
          "+v"(rm[8]), "+v"(rm[9]), "+v"(rm[10]), "+v"(rm[11]), \
          "+v"(rm[12]),"+v"(rm[13]),"+v"(rm[14]), "+v"(rm[15]) \
        :: CLOB_B0); \
    atomicMin(&cmin[(jt0) * 32 + cl],      __float_as_uint(cvA)); \
    atomicMin(&cmin[(jt0) * 32 + 32 + cl], __float_as_uint(cvB)); \
} while (0)

#define REDUCE_B1(jt0) do { float cvA, cvB; \
    asm volatile( \
        "v_min3_f32 %2, %2, v72, v88\n\t"  "v_min3_f32 %3, %3, v73, v89\n\t" \
        "v_min3_f32 %4, %4, v74, v90\n\t"  "v_min3_f32 %5, %5, v75, v91\n\t" \
        "v_min3_f32 %6, %6, v76, v92\n\t"  "v_min3_f32 %7, %7, v77, v93\n\t" \
        "v_min3_f32 %8, %8, v78, v94\n\t"  "v_min3_f32 %9, %9, v79, v95\n\t" \
        "v_min3_f32 %10, %10, v80, v96\n\t" "v_min3_f32 %11, %11, v81, v97\n\t" \
        "v_min3_f32 %12, %12, v82, v98\n\t" "v_min3_f32 %13, %13, v83, v99\n\t" \
        "v_min3_f32 %14, %14, v84, v100\n\t" "v_min3_f32 %15, %15, v85, v101\n\t" \
        "v_min3_f32 %16, %16, v86, v102\n\t" "v_min3_f32 %17, %17, v87, v103\n\t" \
        "v_min3_f32 v72, v72, v73, v74\n\t" "v_min3_f32 v75, v75, v76, v77\n\t" \
        "v_min3_f32 v78, v78, v79, v80\n\t" "v_min3_f32 v81, v81, v82, v83\n\t" \
        "v_min3_f32 v84, v84, v85, v86\n\t" "v_min3_f32 v72, v72, v75, v78\n\t" \
        "v_min3_f32 v81, v81, v84, v87\n\t" "v_min_f32  v72, v72, v81\n\t" \
        "v_max_f32  %0, 0, v72\n\t" \
        "v_min3_f32 v88, v88, v89, v90\n\t" "v_min3_f32 v91, v91, v92, v93\n\t" \
        "v_min3_f32 v94, v94, v95, v96\n\t" "v_min3_f32 v97, v97, v98, v99\n\t" \
        "v_min3_f32 v100, v100, v101, v102\n\t" "v_min3_f32 v88, v88, v91, v94\n\t" \
        "v_min3_f32 v97, v97, v100, v103\n\t" "v_min_f32  v88, v88, v97\n\t" \
        "v_max_f32  %1, 0, v88" \
        : "=&v"(cvA), "=&v"(cvB), \
          "+v"(rm[0]), "+v"(rm[1]), "+v"(rm[2]),  "+v"(rm[3]), \
          "+v"(rm[4]), "+v"(rm[5]), "+v"(rm[6]),  "+v"(rm[7]), \
          "+v"(rm[8]), "+v"(rm[9]), "+v"(rm[10]), "+v"(rm[11]), \
          "+v"(rm[12]),"+v"(rm[13]),"+v"(rm[14]), "+v"(rm[15]) \
        :: CLOB_B1); \
    atomicMin(&cmin[(jt0) * 32 + cl],      __float_as_uint(cvA)); \
    atomicMin(&cmin[(jt0) * 32 + 32 + cl], __float_as_uint(cvB)); \
} while (0)

// ---- prep: B fragments + colm init + acc zero (one node) ----
__global__ __launch_bounds__(256)
void prep_kernel(const float* __restrict__ ov, const float* __restrict__ gov,
                 unsigned short* __restrict__ Bfrag, unsigned int* __restrict__ colm,
                 unsigned int* __restrict__ acc)
{
    const int t = blockIdx.x * 256 + threadIdx.x;       // 65536 = [pg][bt][col]
    if (t < 16) acc[t] = 0u;
    colm[t] = 0x7f7f7f7fu;                              // NPROB*2048 == 65536
    const int col = t & 2047;
    const int bt  = (t >> 11) & 15;
    const int pg  = t >> 15;

    const float* B = (pg ? gov : ov) + ((size_t)bt * VO + col) * 3;
    const float bx = B[0], by = B[1], bz = B[2];
    const float m2x = -2.f * bx, m2y = -2.f * by, m2z = -2.f * bz;
    const float bb  = fmaf(bx, bx, fmaf(by, by, bz * bz));

    const unsigned short hx = bf16_rne(m2x), hy = bf16_rne(m2y), hz = bf16_rne(m2z);
    const unsigned short lx = bf16_rne(m2x - bf16_tof(hx));
    const unsigned short ly = bf16_rne(m2y - bf16_tof(hy));
    const unsigned short lz = bf16_rne(m2z - bf16_tof(hz));
    const unsigned short bh = bf16_rne(bb);
    const unsigned short bl = bf16_rne(bb - bf16_tof(bh));
    const unsigned short one = 0x3F80;

    const int prob = pg * 16 + bt;
    unsigned short* d0 = Bfrag + ((size_t)((prob * 64 + (col >> 5)) * 64 + (col & 31))) * 8;
    const ushort8 w0 = {hx, hy, hz, hx, hy, hz, one, one};   // lane c    (k 0..7)
    const ushort8 w1 = {lx, ly, lz, lx, ly, lz, bh, bl};     // lane c+32 (k 8..15)
    *(ushort8*)d0          = w0;
    *(ushort8*)(d0 + 256)  = w1;
}

// ---- fused mindist: 1728 blocks = 32 probs x 54 row-blocks(128 rows) ----
__global__ __launch_bounds__(256)
void mindist_mfma(const float* __restrict__ hv, const float* __restrict__ ghv,
                  const unsigned short* __restrict__ Bfrag,
                  float* __restrict__ rowm,          // [prob][VH] fp32 d2
                  unsigned int* __restrict__ colm)   // [prob][2048] uint(d2)
{
    __shared__ unsigned int cmin[2048];
    const int tid  = threadIdx.x;
    const int lane = tid & 63;
    const int wave = tid >> 6;
    const int prob = blockIdx.x / RBLK;
    const int rblk = blockIdx.x - prob * RBLK;
    const int pg = prob >> 4, bt = prob & 15;

    for (int i = tid; i < 2048; i += 256) cmin[i] = 0x7f7f7f7fu;

    // ---- A fragment: 32 rows per wave, split-bf16, pad rows -> x=1e4 ----
    const float* A = (pg ? ghv : hv) + (size_t)bt * VH * 3;
    const int row0 = rblk * 128 + wave * 32;
    const int r    = row0 + (lane & 31);
    float x, y, z;
    if (r < VH) { x = A[3*r]; y = A[3*r+1]; z = A[3*r+2]; }
    else        { x = 1.0e4f; y = 0.f;      z = 0.f; }
    const float aa = fmaf(x, x, fmaf(y, y, z * z));
    const unsigned short ahx = bf16_rne(x), ahy = bf16_rne(y), ahz = bf16_rne(z);
    const unsigned short alx = bf16_rne(x - bf16_tof(ahx));
    const unsigned short aly = bf16_rne(y - bf16_tof(ahy));
    const unsigned short alz = bf16_rne(z - bf16_tof(ahz));
    const unsigned short aah = bf16_rne(aa);
    const unsigned short aal = bf16_rne(aa - bf16_tof(aah));
    const int g = lane >> 5;
    ushort8 a8u;
    a8u[0] = ahx; a8u[1] = ahy; a8u[2] = ahz;
    a8u[3] = alx; a8u[4] = aly; a8u[5] = alz;
    a8u[6] = g ? (unsigned short)0x3F80 : aah;
    a8u[7] = g ? (unsigned short)0x3F80 : aal;
    const short8 a8 = (short8)a8u;

    __syncthreads();   // cmin init done

    const short8* bls = (const short8*)(Bfrag + (size_t)prob * (64 * 64 * 8)) + lane;
    const int cl = lane & 31;
#define LD(jt) bls[(jt) * 64]

    float rm[16];
#pragma unroll
    for (int i = 0; i < 16; ++i) rm[i] = 3.0e38f;

    // pipeline: half-step p: MFMA(pair p) ; REDUCE(pair p-1)
    short8 bE0 = LD(0), bE1 = LD(1);
    MFMA_B0(bE0, bE1);                    // pair0 -> bank0
    short8 bO0 = LD(2), bO1 = LD(3);      // pair1

    for (int s = 1; s < 31; s += 2) {
        bE0 = LD(2*s + 2); bE1 = LD(2*s + 3);   // pair s+1
        MFMA_B1(bO0, bO1);                       // pair s
        REDUCE_B0(2*s - 2);                      // pair s-1
        bO0 = LD(2*s + 4); bO1 = LD(2*s + 5);   // pair s+2
        MFMA_B0(bE0, bE1);                       // pair s+1
        REDUCE_B1(2*s);                          // pair s
    }
    MFMA_B1(bO0, bO1);                    // pair31 (tiles 62,63)
    REDUCE_B0(60);                        // pair30
    asm volatile("s_nop 7\n\ts_nop 7");   // spacing for the final bank1 read
    REDUCE_B1(62);                        // pair31
#undef LD

    // ---- row-min butterfly across the 32 col-lanes ----
#pragma unroll
    for (int i = 0; i < 16; ++i) {
        float v = rm[i];
        v = fminf(v, __shfl_xor(v, 1));
        v = fminf(v, __shfl_xor(v, 2));
        v = fminf(v, __shfl_xor(v, 4));
        v = fminf(v, __shfl_xor(v, 8));
        v = fminf(v, __shfl_xor(v, 16));
        rm[i] = v;
    }
    if ((lane & 31) == 0) {       // lanes 0 and 32 hold 16 rows each
        float* rout = rowm + (size_t)prob * VH;
#pragma unroll
        for (int i = 0; i < 16; ++i) {
            const int rr = row0 + (i & 3) + 8 * (i >> 2) + 4 * g;
            if (rr < VH) rout[rr] = fmaxf(rm[i], 0.f);
        }
    }

    __syncthreads();   // all tiles' col atomics done
    unsigned int* gc = colm + (size_t)prob * 2048;
    for (int i = tid; i < 2048; i += 256) atomicMin(&gc[i], cmin[i]);
}

// ---- fused per-element loss + accumulation + last-block finalize ----
#define NBLK_H 431   // ceil(110240/256)
#define NBLK_O 128   // 32768/256
#define NBLK   (NBLK_H + NBLK_O)

__global__ __launch_bounds__(256)
void reduce_finalize(const float* __restrict__ rowm, const unsigned int* __restrict__ colm,
                     float* __restrict__ acc, float* __restrict__ outp)
{
    const int b = blockIdx.x;
    float p2 = 3.0e38f, g2 = 3.0e38f;
    float* a4;
    bool valid;

    if (b < NBLK_H) {
        a4 = acc;
        const int i = b * 256 + threadIdx.x;
        valid = (i < NH);
        if (valid) {
            const int bt = i / VH;
            const int r  = i - bt * VH;
            p2 = rowm[(size_t)bt * VH + r];
            g2 = rowm[(size_t)(16 + bt) * VH + r];
        }
    } else {
        a4 = acc + 4;
        const int i = (b - NBLK_H) * 256 + threadIdx.x;
        valid = true;
        const int bt = i >> 11;
        const int j  = i & 2047;
        p2 = __uint_as_float(colm[(size_t)bt * 2048 + j]);
        g2 = __uint_as_float(colm[(size_t)(16 + bt) * 2048 + j]);
    }

    float t = 0.f, sp = 0.f, sn = 0.f, sh = 0.f;
    if (valid) {
        const float d  = sqrtf(p2);
        const float dg = sqrtf(g2);
        const float tt = (dg < 0.2f) ? 1.f : 0.f;

        const float z = (0.2f - d) * 100.0f;           // (DIST_THR - d)/ALPHA
        float p = 1.0f / (1.0f + expf(-z));
        p = fminf(fmaxf(p, 1e-6f), 1.0f - 1e-6f);
        const float bce = (tt > 0.5f) ? -logf(p) : -logf(1.0f - p);

        const float over = fmaxf(d - 0.1f, 0.0f);      // d - CONTACT_TGT
        const float hub  = (over < 0.01f) ? (0.5f * over * over) / 0.01f
                                          : (over - 0.5f * 0.01f);
        t  = tt;
        sp = tt * bce;
        sn = (1.0f - tt) * bce;
        sh = tt * hub;
    }
    for (int off = 32; off > 0; off >>= 1) {
        t  += __shfl_down(t,  off);
        sp += __shfl_down(sp, off);
        sn += __shfl_down(sn, off);
        sh += __shfl_down(sh, off);
    }
    __shared__ float wsum[4][4];
    const int wid = threadIdx.x >> 6, lane = threadIdx.x & 63;
    if (lane == 0) {
        wsum[wid][0] = t; wsum[wid][1] = sp; wsum[wid][2] = sn; wsum[wid][3] = sh;
    }
    __syncthreads();
    if (threadIdx.x == 0) {
        float s0 = 0, s1 = 0, s2 = 0, s3 = 0;
        for (int w = 0; w < 4; ++w) {
            s0 += wsum[w][0]; s1 += wsum[w][1]; s2 += wsum[w][2]; s3 += wsum[w][3];
        }
        atomicAdd(&a4[0], s0);
        atomicAdd(&a4[1], s1);
        atomicAdd(&a4[2], s2);
        atomicAdd(&a4[3], s3);

        __threadfence();
        const unsigned f = atomicAdd((unsigned int*)&acc[8], 1u);
        if (f == NBLK - 1) {
            float v[8];
            for (int q = 0; q < 8; ++q) v[q] = atomicAdd(&acc[q], 0.0f);
            const float Ph = v[0], SpH = v[1], SnH = v[2], ShH = v[3];
            const float Po = v[4], SpO = v[5], SnO = v[6], ShO = v[7];
            const float Nh = (float)NH, No = (float)NO;

            const float pwH = ((Nh - Ph) + 1e-6f) / (Ph + 1e-6f);
            const float pwO = ((No - Po) + 1e-6f) / (Po + 1e-6f);
            const float bceH = (pwH * SpH + SnH) / Nh;
            const float bceO = (pwO * SpO + SnO) / No;
            const float Lbce = 0.5f * (bceH + bceO);

            const float LdH = (Ph > 0.f) ? ShH / fmaxf(Ph, 1.f) : 0.f;
            const float LdO = (Po > 0.f) ? ShO / fmaxf(Po, 1.f) : 0.f;

            outp[0] = 0.5f * Lbce + (LdH + LdO);
        }
    }
}

extern "C" void kernel_launch(void* const* d_in, const int* in_sizes, int n_in,
                              void* d_out, int out_size, void* d_ws, size_t ws_size,
                              hipStream_t stream)
{
    const float* hv  = (const float*)d_in[0];
    const float* ov  = (const float*)d_in[1];
    const float* ghv = (const float*)d_in[2];
    const float* gov = (const float*)d_in[3];

    unsigned short* Bfrag = (unsigned short*)d_ws;                 // 32*64*64*8 u16 = 2MB
    float*          rowm  = (float*)(Bfrag + NPROB * 64 * 64 * 8); // [32][VH]
    unsigned int*   colm  = (unsigned int*)(rowm + NPROB * VH);    // [32][2048]
    float*          acc   = (float*)(colm + NPROB * 2048);         // 8 sums + ctr

    prep_kernel<<<256, 256, 0, stream>>>(ov, gov, Bfrag, colm, (unsigned int*)acc);

    mindist_mfma<<<NPROB * RBLK, 256, 0, stream>>>(hv, ghv, Bfrag, rowm, colm);

    reduce_finalize<<<NBLK, 256, 0, stream>>>(rowm, colm, acc, (float*)d_out);
}